// Round 12
// baseline (272.272 us; speedup 1.0000x reference)
//
#include <hip/hip_runtime.h>

typedef _Float16 f16;
typedef f16 f16x4 __attribute__((ext_vector_type(4)));
typedef f16 f16x8 __attribute__((ext_vector_type(8)));
typedef float f32x4 __attribute__((ext_vector_type(4)));
typedef float f32x16 __attribute__((ext_vector_type(16)));
typedef unsigned int uint32;

#define FIN  64
#define FOUT 64
#define HI   128
#define WI   128
#define HO   126
#define WO   126
#define HIWI (HI*WI)
#define NPH  16      // phases, 4 input channels each
#define CPH  4
#define TR   8       // tile rows
#define TC   16      // tile cols
#define SR   10      // staged rows (TR+2)
#define SDW  12      // dwords per staged row (10 used, 2 pad)
#define CHSTR (SR*SDW)        // 120 dwords per channel block
#define ONES_OFF (CPH*CHSTR)  // 480: shared 1.0h row (bias slot)
#define XBUF (ONES_OFF+SDW)   // 492 dwords per buffer
#define NUNIT 200             // float4 staging units per phase

// ws: weight B-fragment table f16 [i][ob][lane][8] = 128 KiB.
// k-labeling (validated end-to-end rounds 6/8/9/10, symmetric between operands):
//   k = g*4 + (j&3) + 8*(j>>2), g = lane>>5;  taps k=4*dy+dx (dx<3 real,
//   dx=3 zero-weight), k12 = bias slot (pixel operand supplies 1.0).
// NOTE (round 11 lesson): never take the address of an MFMA result vector
// ((f32x2*)&S) — it allocas S to scratch: 1 GB of spill traffic. Index S[r]
// directly.

__global__ __launch_bounds__(256) void prepass(
    const float* __restrict__ Wf, const float* __restrict__ bf,
    unsigned short* __restrict__ ws)
{
    int t = blockIdx.x * 256 + threadIdx.x;   // 0..8191
    int i  = t >> 7;
    int ob = (t >> 6) & 1;
    int l  = t & 63;
    int g  = l >> 5, n = l & 31;
    int o  = ob * 32 + n;
    unsigned short h[8];
#pragma unroll
    for (int j = 0; j < 8; ++j) {
        int k = g * 4 + (j & 3) + 8 * (j >> 2);
        float v = 0.0f;
        if (k < 12) {
            int dy = k >> 2, dx = k & 3;
            if (dx < 3) v = Wf[((size_t)o * FIN + i) * 9 + dy * 3 + dx];
        } else if (k == 12) {
            v = bf[o * FIN + i];
        }
        f16 hv = (f16)v;
        h[j] = *(unsigned short*)&hv;
    }
    uint4 pk;
    pk.x = h[0] | ((uint32)h[1] << 16);
    pk.y = h[2] | ((uint32)h[3] << 16);
    pk.z = h[4] | ((uint32)h[5] << 16);
    pk.w = h[6] | ((uint32)h[7] << 16);
    *(uint4*)&ws[(size_t)t * 8] = pk;
}

__global__ __launch_bounds__(256, 4) void conv_mfma(
    const float* __restrict__ x,  const float* __restrict__ Wc,
    const float* __restrict__ bc, const unsigned short* __restrict__ ws,
    float* __restrict__ out)
{
    __shared__ __align__(16) union {
        struct { uint32 xsl[2][XBUF]; float wcl[32][68]; } a;  // 12.6 KB
        float ot[32][132];                                     // 16.9 KB
    } sm;

    const int tid = threadIdx.x;
    const int l   = tid & 63, w = tid >> 6;
    const int g   = l >> 5;
    const int m   = l & 31;          // A-row (pixel) on loads; C-col (o) on output
    const int prow = m >> 2;
    // wave-uniform column parity: waves 0..3 own cols {0,2..6},{8..14},{1,3..7},{9..15}
    const int qd   = (w & 1) * 4 + (m & 3);   // first dword of the window
    const int shl  = (w >> 1) * 16;           // alignbit shift: 0 even wave, 16 odd

    // XCD-group swizzle: all 16 blocks sharing (rx,b) -> same fid%8 (same XCD)
    const int fid    = blockIdx.x;
    const int grp    = (fid >> 7) * 8 + (fid & 7);   // 0..63 = rx + 16*b
    const int member = (fid >> 3) & 15;              // cy + 8*oh
    const int rx = grp & 15, b = grp >> 4;
    const int cy = member & 7, oh = member >> 3;
    const int row0 = rx * TR;
    const int col0 = cy * TC;
    const int o_lane = oh * 32 + m;

    // ---- stage Wc [oo][i] (coalesced: Wc input is already [o][i]) ----
#pragma unroll
    for (int k = 0; k < 8; ++k) {
        int idx = tid + k * 256;                      // 0..2047
        sm.a.wcl[idx >> 6][idx & 63] =
            Wc[(size_t)(oh * 32 + (idx >> 6)) * FIN + (idx & 63)];
    }
    // ones rows (bias slot source), both buffers
    if (tid < 2 * SDW) sm.a.xsl[tid / SDW][ONES_OFF + tid % SDW] = 0x3c003c00u;

    // ---- staging map: 200 units, one aligned float4 each ----
    const float* xb = x + (size_t)b * FIN * HIWI;
    const bool stg = (tid < NUNIT);
    int uch = 0, goff = 0, widx = 0;
    if (stg) {
        uch = tid / 50;
        int rem = tid % 50;
        int r = rem / 5, u = rem % 5;
        int gy = min(row0 + r, HI - 1);        // clamped lanes feed discarded outputs
        int gx = min(col0 + 4 * u, WI - 4);
        goff = gy * WI + gx;
        widx = uch * CHSTR + r * SDW + 2 * u;  // even dword -> 8B-aligned write
    }

    // prologue: stage channels 0..3 into buffer 0
    if (stg) {
        f32x4 v = *(const f32x4*)&xb[(size_t)uch * HIWI + goff];
        f16x4 h; h[0] = (f16)v[0]; h[1] = (f16)v[1]; h[2] = (f16)v[2]; h[3] = (f16)v[3];
        *(uint2*)&sm.a.xsl[0][widx] = *(uint2*)&h;
    }

    // B-fragment (weights) prefetch for phase 0
    const uint4* Btab = (const uint4*)ws;
    uint4 BA[CPH], BB[CPH];
#pragma unroll
    for (int ch = 0; ch < CPH; ++ch)
        BA[ch] = Btab[(size_t)(ch * 2 + oh) * 64 + l];

    f32x16 acc = {}, zero = {};

    // hoisted read offsets (per-thread constants)
    const int r1off = (prow + g) * SDW + qd;
    const int r2off = g ? (ONES_OFF + qd) : ((prow + 2) * SDW + qd);
    const int r2str = g ? 0 : CHSTR;

    auto phase = [&](int ph, int cur, uint4 (&Bcur)[CPH], uint4 (&Bnxt)[CPH]) {
        const bool more = (ph + 1 < NPH);
        f32x4 sv = {};
        if (more) {
            const int ib = (ph + 1) * CPH;
            if (stg) sv = *(const f32x4*)&xb[(size_t)(ib + uch) * HIWI + goff];
#pragma unroll
            for (int ch = 0; ch < CPH; ++ch)
                Bnxt[ch] = Btab[(size_t)((ib + ch) * 2 + oh) * 64 + l];
        }

        __syncthreads();   // buf[cur] writes from previous phase visible

        const f32x4 wcq = *(const f32x4*)&sm.a.wcl[m][ph * CPH];
        const uint32* base = sm.a.xsl[cur];

#pragma unroll
        for (int ch = 0; ch < CPH; ++ch) {
            const uint32* r1 = base + ch * CHSTR + r1off;
            const uint32* r2 = base + ch * r2str + r2off;
            uint32 d0 = r1[0], d1 = r1[1], d2 = r1[2];
            uint32 e0 = r2[0], e1 = r2[1], e2 = r2[2];
            uint32 a0 = __builtin_amdgcn_alignbit(d1, d0, shl);
            uint32 a1 = __builtin_amdgcn_alignbit(d2, d1, shl);
            uint32 b0 = __builtin_amdgcn_alignbit(e1, e0, shl);
            uint32 b1 = __builtin_amdgcn_alignbit(e2, e1, shl);
            uint4 auv = {a0, a1, b0, b1};
            f16x8 Af = *(f16x8*)&auv;
            f16x8 Bf = *(f16x8*)&Bcur[ch];
            f32x16 S = __builtin_amdgcn_mfma_f32_32x32x16_f16(Af, Bf, zero, 0, 0, 0);
            const float wcv = wcq[ch];
#pragma unroll
            for (int r = 0; r < 16; ++r)
                acc[r] = fmaf(wcv, fmaxf(S[r], 0.0f), acc[r]);
        }

        if (more && stg) {
            f16x4 h; h[0] = (f16)sv[0]; h[1] = (f16)sv[1];
            h[2] = (f16)sv[2]; h[3] = (f16)sv[3];
            *(uint2*)&sm.a.xsl[cur ^ 1][widx] = *(uint2*)&h;
        }
    };

    for (int ph2 = 0; ph2 < NPH; ph2 += 2) {   // ping-pong: no B-frag rotate movs
        phase(ph2 + 0, 0, BA, BB);
        phase(ph2 + 1, 1, BB, BA);
    }

    __syncthreads();   // xsl/wcl dead -> reuse LDS as transpose buffer

    // ---- transpose: ot[o][px], px row-major in the 8x16 tile ----
    const float bcv = bc[o_lane];
#pragma unroll
    for (int r = 0; r < 16; ++r) {
        int p  = (r & 3) + 8 * (r >> 2) + 4 * g;                 // wave-local pixel
        int px = (p >> 2) * TC + (w & 1) * 8 + 2 * (p & 3) + (w >> 1);
        sm.ot[m][px] = acc[r] + bcv;
    }
    __syncthreads();

    // ---- stores: one 16-col row chunk (64B) per thread ----
    {
        const int oo  = tid >> 3;          // 0..31
        const int seg = tid & 7;           // tile row
        const int o   = oh * 32 + oo;
        const int ho  = row0 + seg;
        if (ho < HO) {
            const float* src = &sm.ot[oo][seg * TC];
            size_t base = ((size_t)(b * FOUT + o) * HO + ho) * WO + col0;
            const int nst = (col0 + TC <= WO) ? TC : (WO - col0);
            for (int c = 0; c < nst; ++c) out[base + c] = src[c];
        }
    }
}

extern "C" void kernel_launch(void* const* d_in, const int* in_sizes, int n_in,
                              void* d_out, int out_size, void* d_ws, size_t ws_size,
                              hipStream_t stream) {
    const float* x  = (const float*)d_in[0];
    const float* Wf = (const float*)d_in[1];
    const float* bf = (const float*)d_in[2];
    const float* Wc = (const float*)d_in[3];
    const float* bc = (const float*)d_in[4];
    float* out = (float*)d_out;
    unsigned short* ws = (unsigned short*)d_ws;

    hipLaunchKernelGGL(prepass, dim3(32), dim3(256), 0, stream, Wf, bf, ws);

    // 1024 blocks: 16 rx x (8 cy x 2 oh) x 4 b, XCD-group swizzled
    hipLaunchKernelGGL(conv_mfma, dim3(1024), dim3(256), 0, stream,
                       x, Wc, bc, ws, out);
}

// Round 13
// 53.631 us; speedup vs baseline: 5.0768x; 5.0768x over previous
//
#include <hip/hip_runtime.h>

typedef _Float16 f16;
typedef f16 f16x4 __attribute__((ext_vector_type(4)));
typedef f16 f16x8 __attribute__((ext_vector_type(8)));
typedef float f32x4 __attribute__((ext_vector_type(4)));
typedef float f32x16 __attribute__((ext_vector_type(16)));
typedef unsigned int uint32;

#define FIN  64
#define FOUT 64
#define HI   128
#define WI   128
#define HO   126
#define WO   126
#define HIWI (HI*WI)
#define NPH  16      // phases, 4 input channels each
#define CPH  4
#define TR   8       // tile rows
#define TC   16      // tile cols
#define SR   10      // staged rows (TR+2)
#define SDW  12      // dwords per staged row (10 used, 2 pad)
#define CHSTR (SR*SDW)        // 120 dwords per channel block
#define ONES_OFF (CPH*CHSTR)  // 480: shared 1.0h row (bias slot)
#define XBUF (ONES_OFF+SDW)   // 492 dwords per buffer
#define NUNIT 200             // float4 staging units per phase

// ws: weight B-fragment table f16 [i][ob][lane][8] = 128 KiB.
// k-labeling (validated rounds 6/8/9/10): k = g*4+(j&3)+8*(j>>2), g=lane>>5;
// taps k=4*dy+dx (dx<3 real, dx=3 zero-weight), k12 = bias (pixel side = 1.0h).
// LESSONS: (r11) never take the address of an MFMA result vector -> scratch.
// (r12) never pass register arrays by reference (lambda array-ref params) ->
// SROA fails, arrays alloca'd to scratch, ~0.5 GB spill traffic. Plain loop +
// explicit rotation keeps them in VGPRs.

__global__ __launch_bounds__(256) void prepass(
    const float* __restrict__ Wf, const float* __restrict__ bf,
    unsigned short* __restrict__ ws)
{
    int t = blockIdx.x * 256 + threadIdx.x;   // 0..8191
    int i  = t >> 7;
    int ob = (t >> 6) & 1;
    int l  = t & 63;
    int g  = l >> 5, n = l & 31;
    int o  = ob * 32 + n;
    unsigned short h[8];
#pragma unroll
    for (int j = 0; j < 8; ++j) {
        int k = g * 4 + (j & 3) + 8 * (j >> 2);
        float v = 0.0f;
        if (k < 12) {
            int dy = k >> 2, dx = k & 3;
            if (dx < 3) v = Wf[((size_t)o * FIN + i) * 9 + dy * 3 + dx];
        } else if (k == 12) {
            v = bf[o * FIN + i];
        }
        f16 hv = (f16)v;
        h[j] = *(unsigned short*)&hv;
    }
    uint4 pk;
    pk.x = h[0] | ((uint32)h[1] << 16);
    pk.y = h[2] | ((uint32)h[3] << 16);
    pk.z = h[4] | ((uint32)h[5] << 16);
    pk.w = h[6] | ((uint32)h[7] << 16);
    *(uint4*)&ws[(size_t)t * 8] = pk;
}

__global__ __launch_bounds__(256, 4) void conv_mfma(
    const float* __restrict__ x,  const float* __restrict__ Wc,
    const float* __restrict__ bc, const unsigned short* __restrict__ ws,
    float* __restrict__ out)
{
    __shared__ __align__(16) union {
        struct { uint32 xsl[2][XBUF]; float wcl[32][68]; } a;  // 12.6 KB
        float ot[32][132];                                     // 16.9 KB
    } sm;

    const int tid = threadIdx.x;
    const int l   = tid & 63, w = tid >> 6;
    const int g   = l >> 5;
    const int m   = l & 31;          // A-row (pixel) on loads; C-col (o) on output
    const int prow = m >> 2;
    // wave-uniform column parity: even waves own even cols, odd waves odd cols
    const int qd   = (w & 1) * 4 + (m & 3);   // first dword of the window
    const int shl  = (w >> 1) * 16;           // alignbit shift: 0 or 16 (uniform)

    // XCD-group swizzle: all 16 blocks sharing (rx,b) -> same fid%8 (same XCD)
    const int fid    = blockIdx.x;
    const int grp    = (fid >> 7) * 8 + (fid & 7);   // 0..63 = rx + 16*b
    const int member = (fid >> 3) & 15;              // cy + 8*oh
    const int rx = grp & 15, b = grp >> 4;
    const int cy = member & 7, oh = member >> 3;
    const int row0 = rx * TR;
    const int col0 = cy * TC;
    const int o_lane = oh * 32 + m;

    // ---- stage Wc [oo][i] (coalesced: Wc input is already [o][i]) ----
#pragma unroll
    for (int k = 0; k < 8; ++k) {
        int idx = tid + k * 256;                      // 0..2047
        sm.a.wcl[idx >> 6][idx & 63] =
            Wc[(size_t)(oh * 32 + (idx >> 6)) * FIN + (idx & 63)];
    }
    // ones rows (bias slot source), both buffers
    if (tid < 2 * SDW) sm.a.xsl[tid / SDW][ONES_OFF + tid % SDW] = 0x3c003c00u;

    // ---- staging map: 200 units, one aligned float4 each ----
    const float* xb = x + (size_t)b * FIN * HIWI;
    const bool stg = (tid < NUNIT);
    int uch = 0, goff = 0, widx = 0;
    if (stg) {
        uch = tid / 50;
        int rem = tid % 50;
        int r = rem / 5, u = rem % 5;
        int gy = min(row0 + r, HI - 1);        // clamped lanes feed discarded outputs
        int gx = min(col0 + 4 * u, WI - 4);
        goff = gy * WI + gx;
        widx = uch * CHSTR + r * SDW + 2 * u;  // even dword -> 8B-aligned write
    }

    // prologue: stage channels 0..3 into buffer 0
    if (stg) {
        f32x4 v = *(const f32x4*)&xb[(size_t)uch * HIWI + goff];
        f16x4 h; h[0] = (f16)v[0]; h[1] = (f16)v[1]; h[2] = (f16)v[2]; h[3] = (f16)v[3];
        *(uint2*)&sm.a.xsl[0][widx] = *(uint2*)&h;
    }

    // B-fragment (weights) prefetch for phase 0
    const uint4* Btab = (const uint4*)ws;
    uint4 Bc[CPH], Bn[CPH];
#pragma unroll
    for (int ch = 0; ch < CPH; ++ch)
        Bc[ch] = Btab[(size_t)(ch * 2 + oh) * 64 + l];

    f32x16 acc = {}, zero = {};

    // hoisted read offsets (per-thread constants)
    const int r1off = (prow + g) * SDW + qd;
    const int r2off = g ? (ONES_OFF + qd) : ((prow + 2) * SDW + qd);
    const int r2str = g ? 0 : CHSTR;

    for (int ph = 0; ph < NPH; ++ph) {         // plain loop: arrays stay in VGPRs
        const int cur = ph & 1;
        const bool more = (ph + 1 < NPH);

        f32x4 sv = {};
        if (more) {
            const int ib = (ph + 1) * CPH;
            if (stg) sv = *(const f32x4*)&xb[(size_t)(ib + uch) * HIWI + goff];
#pragma unroll
            for (int ch = 0; ch < CPH; ++ch)
                Bn[ch] = Btab[(size_t)((ib + ch) * 2 + oh) * 64 + l];
        }

        __syncthreads();   // buf[cur] writes from previous phase visible

        const f32x4 wcq = *(const f32x4*)&sm.a.wcl[m][ph * CPH];
        const uint32* base = sm.a.xsl[cur];

#pragma unroll
        for (int ch = 0; ch < CPH; ++ch) {
            const uint32* r1 = base + ch * CHSTR + r1off;
            const uint32* r2 = base + ch * r2str + r2off;
            uint32 d0 = r1[0], d1 = r1[1], d2 = r1[2];
            uint32 e0 = r2[0], e1 = r2[1], e2 = r2[2];
            uint32 a0 = __builtin_amdgcn_alignbit(d1, d0, shl);
            uint32 a1 = __builtin_amdgcn_alignbit(d2, d1, shl);
            uint32 b0 = __builtin_amdgcn_alignbit(e1, e0, shl);
            uint32 b1 = __builtin_amdgcn_alignbit(e2, e1, shl);
            uint4 auv = {a0, a1, b0, b1};
            f16x8 Af = *(f16x8*)&auv;
            f16x8 Bf = *(f16x8*)&Bc[ch];
            f32x16 S = __builtin_amdgcn_mfma_f32_32x32x16_f16(Af, Bf, zero, 0, 0, 0);
            const float wcv = wcq[ch];
#pragma unroll
            for (int r = 0; r < 16; ++r)
                acc[r] = fmaf(wcv, fmaxf(S[r], 0.0f), acc[r]);
        }

        if (more) {
            if (stg) {
                f16x4 h; h[0] = (f16)sv[0]; h[1] = (f16)sv[1];
                h[2] = (f16)sv[2]; h[3] = (f16)sv[3];
                *(uint2*)&sm.a.xsl[cur ^ 1][widx] = *(uint2*)&h;
            }
#pragma unroll
            for (int ch = 0; ch < CPH; ++ch) Bc[ch] = Bn[ch];
        }
    }

    __syncthreads();   // xsl/wcl dead -> reuse LDS as transpose buffer

    // ---- transpose: ot[o][px], px row-major in the 8x16 tile ----
    const float bcv = bc[o_lane];
#pragma unroll
    for (int r = 0; r < 16; ++r) {
        int p  = (r & 3) + 8 * (r >> 2) + 4 * g;                 // wave-local pixel
        int px = (p >> 2) * TC + (w & 1) * 8 + 2 * (p & 3) + (w >> 1);
        sm.ot[m][px] = acc[r] + bcv;
    }
    __syncthreads();

    // ---- stores: one 16-col row chunk (64B) per thread ----
    {
        const int oo  = tid >> 3;          // 0..31
        const int seg = tid & 7;           // tile row
        const int o   = oh * 32 + oo;
        const int ho  = row0 + seg;
        if (ho < HO) {
            const float* src = &sm.ot[oo][seg * TC];
            size_t base = ((size_t)(b * FOUT + o) * HO + ho) * WO + col0;
            const int nst = (col0 + TC <= WO) ? TC : (WO - col0);
            for (int c = 0; c < nst; ++c) out[base + c] = src[c];
        }
    }
}

extern "C" void kernel_launch(void* const* d_in, const int* in_sizes, int n_in,
                              void* d_out, int out_size, void* d_ws, size_t ws_size,
                              hipStream_t stream) {
    const float* x  = (const float*)d_in[0];
    const float* Wf = (const float*)d_in[1];
    const float* bf = (const float*)d_in[2];
    const float* Wc = (const float*)d_in[3];
    const float* bc = (const float*)d_in[4];
    float* out = (float*)d_out;
    unsigned short* ws = (unsigned short*)d_ws;

    hipLaunchKernelGGL(prepass, dim3(32), dim3(256), 0, stream, Wf, bf, ws);

    // 1024 blocks: 16 rx x (8 cy x 2 oh) x 4 b, XCD-group swizzled
    hipLaunchKernelGGL(conv_mfma, dim3(1024), dim3(256), 0, stream,
                       x, Wc, bc, ws, out);
}